// Round 16
// baseline (5315.504 us; speedup 1.0000x reference)
//
#include <hip/hip_runtime.h>

#define T_STEPS 12
#define NN      50000
#define EE      800000
#define IN_F    12
#define TF12    (T_STEPS * IN_F)
#define HID     128
#define G3      384
#define BB      4096
#define AF_     10
#define BN_EPS  1e-5f
#define LPAD    136
#define NBLK    ((NN + 63) / 64)

typedef unsigned short ushort_t;
typedef __attribute__((ext_vector_type(8))) short bf16x8;
typedef __attribute__((ext_vector_type(4))) float f32x4;

#define MFMA(a, b, c) __builtin_amdgcn_mfma_f32_16x16x32_bf16((a), (b), (c), 0, 0, 0)
#define L2E 1.4426950408889634f

__device__ inline float b2f(ushort_t u) { return __uint_as_float(((unsigned)u) << 16); }
__device__ inline float b2f_lo(unsigned u) { return __uint_as_float(u << 16); }
__device__ inline float b2f_hi(unsigned u) { return __uint_as_float(u & 0xffff0000u); }
__device__ inline ushort_t f2b(float f) {
    unsigned u = __float_as_uint(f);
    return (ushort_t)((u + 0x7fffu + ((u >> 16) & 1u)) >> 16);
}
__device__ inline float sigm(float x) {
    return __builtin_amdgcn_rcpf(1.f + __builtin_amdgcn_exp2f(-x * L2E));
}
__device__ inline float ftanh(float x) {
    float xx = fminf(fmaxf(x, -15.f), 15.f);
    float t = __builtin_amdgcn_exp2f(2.f * L2E * xx);
    return (t - 1.f) * __builtin_amdgcn_rcpf(t + 1.f);
}

#define ALIGN_UP(x) (((x) + 255) & ~(size_t)255)
#define SZ_DEG    ALIGN_UP((size_t)NN * 4)
#define SZ_RP     ALIGN_UP((size_t)(NN + 1) * 4)
#define SZ_CUR    ALIGN_UP((size_t)NN * 4)
#define SZ_COL    ALIGN_UP((size_t)EE * 4)
#define SZ_XT     ALIGN_UP((size_t)NN * TF12 * 4)
#define SZ_EMB    ALIGN_UP((size_t)T_STEPS * NN * HID * 2)
#define SZ_NHB    ALIGN_UP((size_t)NN * HID * 2)
#define SZ_W128   ALIGN_UP((size_t)HID * HID * 2)
#define SZ_WGRU   ALIGN_UP((size_t)G3 * HID * 2)
#define WS_NEED   (SZ_DEG + SZ_RP + SZ_CUR + SZ_COL + 2 * SZ_XT + SZ_EMB + 3 * SZ_NHB + 3 * SZ_W128 + 2 * SZ_WGRU)

__device__ __align__(256) char g_static_pool[WS_NEED];

// ---------------- bail path ----------------
__global__ void zero_out_kernel(float* out, int n) {
    int i = blockIdx.x * blockDim.x + threadIdx.x;
    if (i < n) out[i] = 0.f;
}

// ---------------- weights fp32 -> bf16 ----------------
__global__ void cvt5_kernel(const float* s0, ushort_t* d0, int n0,
                            const float* s1, ushort_t* d1, int n1,
                            const float* s2, ushort_t* d2, int n2,
                            const float* s3, ushort_t* d3, int n3,
                            const float* s4, ushort_t* d4, int n4) {
    int i = blockIdx.x * blockDim.x + threadIdx.x;
    if (i < n0) d0[i] = f2b(s0[i]);
    i -= n0;
    if (i >= 0 && i < n1) d1[i] = f2b(s1[i]);
    i -= n1;
    if (i >= 0 && i < n2) d2[i] = f2b(s2[i]);
    i -= n2;
    if (i >= 0 && i < n3) d3[i] = f2b(s3[i]);
    i -= n3;
    if (i >= 0 && i < n4) d4[i] = f2b(s4[i]);
}

// ---------------- init ----------------
__global__ void init_kernel(int* deg, ushort_t* h1, ushort_t* h2) {
    int i = blockIdx.x * blockDim.x + threadIdx.x;
    if (i < NN) deg[i] = 0;
    if (i < NN * HID) { h1[i] = 0; h2[i] = 0; }
}

// ---------------- CSR build ----------------
__global__ void hist_kernel(const int* __restrict__ dst, int* __restrict__ deg, int E) {
    int e = blockIdx.x * blockDim.x + threadIdx.x;
    if (e < E) {
        unsigned d = (unsigned)dst[e];
        if (d < NN) atomicAdd(&deg[d], 1);
    }
}

__global__ __launch_bounds__(1024) void scan_kernel(const int* __restrict__ deg,
                                                    int* __restrict__ row_ptr,
                                                    int* __restrict__ cursor, int n) {
    __shared__ int wsum[16];
    __shared__ int carry_s;
    int tid = threadIdx.x;
    int wid = tid >> 6, lane = tid & 63;
    if (tid == 0) { carry_s = 0; row_ptr[0] = 0; }
    __syncthreads();
    for (int base = 0; base < n; base += 1024) {
        int i = base + tid;
        int v = (i < n) ? deg[i] : 0;
        int x = v;
#pragma unroll
        for (int off = 1; off < 64; off <<= 1) {
            int t = __shfl_up(x, (unsigned)off);
            if (lane >= off) x += t;
        }
        if (lane == 63) wsum[wid] = x;
        __syncthreads();
        if (tid == 0) {
            int a = 0;
#pragma unroll
            for (int w = 0; w < 16; ++w) { int t = wsum[w]; wsum[w] = a; a += t; }
        }
        __syncthreads();
        int incl = carry_s + wsum[wid] + x;
        if (i < n) {
            row_ptr[i + 1] = incl;
            cursor[i] = incl - v;
        }
        __syncthreads();
        if (tid == 1023) carry_s = incl;
        __syncthreads();
    }
}

__global__ void scatter_kernel(const int* __restrict__ src, const int* __restrict__ dst,
                               int* __restrict__ cursor, int* __restrict__ col, int E) {
    int e = blockIdx.x * blockDim.x + threadIdx.x;
    if (e < E) {
        unsigned d = (unsigned)dst[e];
        if (d < NN) {
            int pos = atomicAdd(&cursor[d], 1);
            if ((unsigned)pos < (unsigned)EE) col[pos] = src[e];
        }
    }
}

// ---------------- transpose x: xT[n][t*12+f] = x[t][n][f] ----------------
__global__ void transpose_x_kernel(const float* __restrict__ x_seq, float* __restrict__ xT) {
    int g = blockIdx.x * blockDim.x + threadIdx.x;
    if (g >= NN * TF12) return;
    int n = g / TF12;
    int u = g - n * TF12;
    int t = u / IN_F;
    int f = u - t * IN_F;
    xT[g] = x_seq[(size_t)t * NN * IN_F + (size_t)n * IN_F + f];
}

// ---------------- agg12t: wave per node, ALL 12 planes in ONE edge-walk ----------------
__global__ __launch_bounds__(512) void agg12t_kernel(const float* __restrict__ xT,
                                                     const int* __restrict__ rp,
                                                     const int* __restrict__ col,
                                                     float* __restrict__ xagg, int E) {
    int node = blockIdx.x * 8 + (threadIdx.x >> 6);
    int lane = threadIdx.x & 63;
    if (node >= NN) return;
    const float2* pself = (const float2*)(xT + (size_t)node * TF12);
    float2 a = pself[lane];
    float a2 = (lane < 16) ? xT[(size_t)node * TF12 + 128 + lane] : 0.f;
    int e0 = rp[node], e1 = rp[node + 1];
    if (e1 > E) e1 = E;
    int e = e0;
    for (; e + 1 < e1; e += 2) {
        unsigned c0 = (unsigned)col[e], c1 = (unsigned)col[e + 1];
        c0 = (c0 < NN) ? c0 : 0; c1 = (c1 < NN) ? c1 : 0;
        const float2* p0 = (const float2*)(xT + (size_t)c0 * TF12);
        const float2* p1 = (const float2*)(xT + (size_t)c1 * TF12);
        float2 v0 = p0[lane];
        float2 v1 = p1[lane];
        a.x += v0.x + v1.x;
        a.y += v0.y + v1.y;
        if (lane < 16)
            a2 += xT[(size_t)c0 * TF12 + 128 + lane] + xT[(size_t)c1 * TF12 + 128 + lane];
    }
    for (; e < e1; ++e) {
        unsigned c = (unsigned)col[e];
        if (c < NN) {
            const float2* pn = (const float2*)(xT + (size_t)c * TF12);
            float2 v = pn[lane];
            a.x += v.x;
            a.y += v.y;
            if (lane < 16) a2 += xT[(size_t)c * TF12 + 128 + lane];
        }
    }
    ((float2*)(xagg + (size_t)node * TF12))[lane] = a;
    if (lane < 16) xagg[(size_t)node * TF12 + 128 + lane] = a2;
}

// ---------------- conv1 compute for ALL timesteps (input: transposed aggregate) ----------------
__global__ __launch_bounds__(512) void conv1c_all_kernel(const float* __restrict__ xagg,
                                                         ushort_t* __restrict__ emb,
                                                         const float* __restrict__ W1, const float* __restrict__ b1,
                                                         const float* __restrict__ gg, const float* __restrict__ be,
                                                         const float* __restrict__ rm, const float* __restrict__ rv,
                                                         const ushort_t* __restrict__ w2b, const float* __restrict__ b2) {
    __shared__ float xs[64][IN_F + 1];
    __shared__ ushort_t l1[64][LPAD];
    int t = blockIdx.y;
    ushort_t* et = emb + (size_t)t * NN * HID;
    int tid = threadIdx.x;
    int r0 = blockIdx.x * 64;
    for (int u = tid; u < 64 * IN_F; u += 512) {
        int r = u / IN_F, f = u - r * IN_F;
        int row = r0 + r;
        xs[r][f] = (row < NN) ? xagg[(size_t)row * TF12 + t * IN_F + f] : 0.f;
    }
    __syncthreads();
    {
        int j = tid & 127, rb = tid >> 7;
        float sc = gg[j] * rsqrtf(rv[j] + BN_EPS);
        float sh = be[j] - rm[j] * sc;
        float bj = b1[j];
        float wreg[IN_F];
#pragma unroll
        for (int k = 0; k < IN_F; ++k) wreg[k] = W1[j * IN_F + k];
#pragma unroll
        for (int q = 0; q < 16; ++q) {
            int r = rb + q * 4;
            float s = bj;
#pragma unroll
            for (int k = 0; k < IN_F; ++k) s += xs[r][k] * wreg[k];
            s = fmaxf(s, 0.f);
            l1[r][j] = f2b(s * sc + sh);
        }
    }
    __syncthreads();
    {
        int wave = tid >> 6, lane = tid & 63, li = lane & 15, ks = lane >> 4;
        int jc = wave * 16 + li;
        const ushort_t* pw = w2b + (size_t)jc * HID + ks * 8;
        f32x4 A0 = {0,0,0,0}, A1 = {0,0,0,0}, A2 = {0,0,0,0}, A3 = {0,0,0,0};
#pragma unroll
        for (int k0 = 0; k0 < HID; k0 += 32) {
            bf16x8 wf = *(const bf16x8*)(pw + k0);
            bf16x8 a0 = *(const bf16x8*)&l1[li][ks * 8 + k0];
            bf16x8 a1 = *(const bf16x8*)&l1[li + 16][ks * 8 + k0];
            bf16x8 a2 = *(const bf16x8*)&l1[li + 32][ks * 8 + k0];
            bf16x8 a3 = *(const bf16x8*)&l1[li + 48][ks * 8 + k0];
            A0 = MFMA(a0, wf, A0); A1 = MFMA(a1, wf, A1);
            A2 = MFMA(a2, wf, A2); A3 = MFMA(a3, wf, A3);
        }
        float bj = b2[jc];
#pragma unroll
        for (int q = 0; q < 4; ++q) {
            int rA = r0 + ks * 4 + q, rB = rA + 16, rC = rA + 32, rD = rA + 48;
            if (rA < NN) et[(size_t)rA * HID + jc] = f2b(fmaxf(A0[q] + bj, 0.f));
            if (rB < NN) et[(size_t)rB * HID + jc] = f2b(fmaxf(A1[q] + bj, 0.f));
            if (rC < NN) et[(size_t)rC * HID + jc] = f2b(fmaxf(A2[q] + bj, 0.f));
            if (rD < NN) et[(size_t)rD * HID + jc] = f2b(fmaxf(A3[q] + bj, 0.f));
        }
    }
}

// ---------------- GRU body: h(rows blk*64..+64) <- GRU(x, h), in place ----------------
__device__ __forceinline__ void gru_body(const ushort_t* __restrict__ x,
                                         ushort_t* __restrict__ h,
                                         const ushort_t* __restrict__ wih,
                                         const ushort_t* __restrict__ whh,
                                         const float* __restrict__ bih,
                                         const float* __restrict__ bhh, int blk) {
    int tid = threadIdx.x;
    int wave = tid >> 6, lane = tid & 63, li = lane & 15, ks = lane >> 4;
    int r0 = blk * 64;
    int jc = wave * 16 + li;
    const ushort_t* px[4];
    const ushort_t* ph[4];
#pragma unroll
    for (int tt = 0; tt < 4; ++tt) {
        int ra = min(r0 + tt * 16 + li, NN - 1);
        px[tt] = x + (size_t)ra * HID + ks * 8;
        ph[tt] = h + (size_t)ra * HID + ks * 8;
    }
    const ushort_t* pwr = wih + (size_t)jc * HID + ks * 8;
    const ushort_t* pwz = wih + (size_t)(HID + jc) * HID + ks * 8;
    const ushort_t* pwn = wih + (size_t)(2 * HID + jc) * HID + ks * 8;
    const ushort_t* pvr = whh + (size_t)jc * HID + ks * 8;
    const ushort_t* pvz = whh + (size_t)(HID + jc) * HID + ks * 8;
    const ushort_t* pvn = whh + (size_t)(2 * HID + jc) * HID + ks * 8;
    f32x4 Ir[4], Iz[4], In[4], Hr[4], Hz[4], Hn[4];
#pragma unroll
    for (int tt = 0; tt < 4; ++tt) {
        Ir[tt] = (f32x4){0,0,0,0}; Iz[tt] = (f32x4){0,0,0,0}; In[tt] = (f32x4){0,0,0,0};
        Hr[tt] = (f32x4){0,0,0,0}; Hz[tt] = (f32x4){0,0,0,0}; Hn[tt] = (f32x4){0,0,0,0};
    }
    __builtin_amdgcn_s_setprio(1);
#pragma unroll
    for (int k0 = 0; k0 < HID; k0 += 32) {
        bf16x8 wr = *(const bf16x8*)(pwr + k0);
        bf16x8 wz = *(const bf16x8*)(pwz + k0);
        bf16x8 wn = *(const bf16x8*)(pwn + k0);
        bf16x8 vr = *(const bf16x8*)(pvr + k0);
        bf16x8 vz = *(const bf16x8*)(pvz + k0);
        bf16x8 vn = *(const bf16x8*)(pvn + k0);
#pragma unroll
        for (int tt = 0; tt < 4; ++tt) {
            bf16x8 xf = *(const bf16x8*)(px[tt] + k0);
            bf16x8 hf = *(const bf16x8*)(ph[tt] + k0);
            Ir[tt] = MFMA(xf, wr, Ir[tt]);
            Iz[tt] = MFMA(xf, wz, Iz[tt]);
            In[tt] = MFMA(xf, wn, In[tt]);
            Hr[tt] = MFMA(hf, vr, Hr[tt]);
            Hz[tt] = MFMA(hf, vz, Hz[tt]);
            Hn[tt] = MFMA(hf, vn, Hn[tt]);
        }
    }
    __builtin_amdgcn_s_setprio(0);
    float bi_r = bih[jc], bi_z = bih[HID + jc], bi_n = bih[2 * HID + jc];
    float bh_r = bhh[jc], bh_z = bhh[HID + jc], bh_n = bhh[2 * HID + jc];
    float hold[4][4];
#pragma unroll
    for (int tt = 0; tt < 4; ++tt)
#pragma unroll
        for (int q = 0; q < 4; ++q) {
            int rr = min(r0 + tt * 16 + ks * 4 + q, NN - 1);
            hold[tt][q] = b2f(h[(size_t)rr * HID + jc]);
        }
    __syncthreads();  // all block-wide reads of h complete before in-place writes
#pragma unroll
    for (int tt = 0; tt < 4; ++tt)
#pragma unroll
        for (int q = 0; q < 4; ++q) {
            int row = r0 + tt * 16 + ks * 4 + q;
            float rg = sigm(Ir[tt][q] + bi_r + Hr[tt][q] + bh_r);
            float zg = sigm(Iz[tt][q] + bi_z + Hz[tt][q] + bh_z);
            float ng = ftanh(In[tt][q] + bi_n + rg * (Hn[tt][q] + bh_n));
            float hv = (1.f - zg) * ng + zg * hold[tt][q];
            if (row < NN) h[(size_t)row * HID + jc] = f2b(hv);
        }
}

// ---------------- mega2 body: conv2-l1 (+h-side GRU overlap) -> l2 -> GRU2, rows blk*64..+64 ----------------
__device__ __forceinline__ void mega2_body(const ushort_t* __restrict__ xin2,
                                           ushort_t* __restrict__ h2,
                                           const ushort_t* __restrict__ w1b, const float* __restrict__ b1,
                                           const float* __restrict__ gg, const float* __restrict__ be,
                                           const float* __restrict__ rm, const float* __restrict__ rv,
                                           const ushort_t* __restrict__ w2b, const float* __restrict__ b2,
                                           const ushort_t* __restrict__ wih, const ushort_t* __restrict__ whh,
                                           const float* __restrict__ bih, const float* __restrict__ bhh, int blk) {
    __shared__ ushort_t bufA[64][LPAD];
    __shared__ ushort_t bufB[64][LPAD];
    int tid = threadIdx.x;
    int wave = tid >> 6, lane = tid & 63, li = lane & 15, ks = lane >> 4;
    int r0 = blk * 64;
    int jc = wave * 16 + li;
    f32x4 Hr[4], Hz[4], Hn[4], C1[4];
#pragma unroll
    for (int tt = 0; tt < 4; ++tt) {
        Hr[tt] = (f32x4){0,0,0,0}; Hz[tt] = (f32x4){0,0,0,0};
        Hn[tt] = (f32x4){0,0,0,0}; C1[tt] = (f32x4){0,0,0,0};
    }
    {
        const ushort_t* pw1 = w1b + (size_t)jc * HID + ks * 8;
        const ushort_t* pvr = whh + (size_t)jc * HID + ks * 8;
        const ushort_t* pvz = whh + (size_t)(HID + jc) * HID + ks * 8;
        const ushort_t* pvn = whh + (size_t)(2 * HID + jc) * HID + ks * 8;
        const ushort_t* pa[4];
        const ushort_t* ph[4];
#pragma unroll
        for (int tt = 0; tt < 4; ++tt) {
            int ra = min(r0 + tt * 16 + li, NN - 1);
            pa[tt] = xin2 + (size_t)ra * HID + ks * 8;
            ph[tt] = h2 + (size_t)ra * HID + ks * 8;
        }
        __builtin_amdgcn_s_setprio(1);
#pragma unroll
        for (int k0 = 0; k0 < HID; k0 += 32) {
            bf16x8 w1f = *(const bf16x8*)(pw1 + k0);
            bf16x8 vr = *(const bf16x8*)(pvr + k0);
            bf16x8 vz = *(const bf16x8*)(pvz + k0);
            bf16x8 vn = *(const bf16x8*)(pvn + k0);
#pragma unroll
            for (int tt = 0; tt < 4; ++tt) {
                bf16x8 af = *(const bf16x8*)(pa[tt] + k0);
                bf16x8 hf = *(const bf16x8*)(ph[tt] + k0);
                C1[tt] = MFMA(af, w1f, C1[tt]);
                Hr[tt] = MFMA(hf, vr, Hr[tt]);
                Hz[tt] = MFMA(hf, vz, Hz[tt]);
                Hn[tt] = MFMA(hf, vn, Hn[tt]);
            }
        }
        __builtin_amdgcn_s_setprio(0);
    }
    float hold[4][4];
#pragma unroll
    for (int tt = 0; tt < 4; ++tt)
#pragma unroll
        for (int q = 0; q < 4; ++q) {
            int rr = min(r0 + tt * 16 + ks * 4 + q, NN - 1);
            hold[tt][q] = b2f(h2[(size_t)rr * HID + jc]);
        }
    {
        float sc = gg[jc] * rsqrtf(rv[jc] + BN_EPS);
        float sh = be[jc] - rm[jc] * sc;
        float bj = b1[jc];
#pragma unroll
        for (int tt = 0; tt < 4; ++tt)
#pragma unroll
            for (int q = 0; q < 4; ++q)
                bufB[tt * 16 + ks * 4 + q][jc] = f2b(fmaxf(C1[tt][q] + bj, 0.f) * sc + sh);
    }
    __syncthreads();
    {
        const ushort_t* pw2 = w2b + (size_t)jc * HID + ks * 8;
        f32x4 C2[4];
#pragma unroll
        for (int tt = 0; tt < 4; ++tt) C2[tt] = (f32x4){0,0,0,0};
        __builtin_amdgcn_s_setprio(1);
#pragma unroll
        for (int k0 = 0; k0 < HID; k0 += 32) {
            bf16x8 wf = *(const bf16x8*)(pw2 + k0);
#pragma unroll
            for (int tt = 0; tt < 4; ++tt) {
                bf16x8 af = *(const bf16x8*)&bufB[li + 16 * tt][ks * 8 + k0];
                C2[tt] = MFMA(af, wf, C2[tt]);
            }
        }
        __builtin_amdgcn_s_setprio(0);
        float bj = b2[jc];
#pragma unroll
        for (int tt = 0; tt < 4; ++tt)
#pragma unroll
            for (int q = 0; q < 4; ++q)
                bufA[tt * 16 + ks * 4 + q][jc] = f2b(fmaxf(C2[tt][q] + bj, 0.f));
    }
    __syncthreads();
    {
        const ushort_t* pwr = wih + (size_t)jc * HID + ks * 8;
        const ushort_t* pwz = wih + (size_t)(HID + jc) * HID + ks * 8;
        const ushort_t* pwn = wih + (size_t)(2 * HID + jc) * HID + ks * 8;
        f32x4 Ir[4], Iz[4], In[4];
#pragma unroll
        for (int tt = 0; tt < 4; ++tt) {
            Ir[tt] = (f32x4){0,0,0,0}; Iz[tt] = (f32x4){0,0,0,0}; In[tt] = (f32x4){0,0,0,0};
        }
        __builtin_amdgcn_s_setprio(1);
#pragma unroll
        for (int k0 = 0; k0 < HID; k0 += 32) {
            bf16x8 wr = *(const bf16x8*)(pwr + k0);
            bf16x8 wz = *(const bf16x8*)(pwz + k0);
            bf16x8 wn = *(const bf16x8*)(pwn + k0);
#pragma unroll
            for (int tt = 0; tt < 4; ++tt) {
                bf16x8 xf = *(const bf16x8*)&bufA[li + 16 * tt][ks * 8 + k0];
                Ir[tt] = MFMA(xf, wr, Ir[tt]);
                Iz[tt] = MFMA(xf, wz, Iz[tt]);
                In[tt] = MFMA(xf, wn, In[tt]);
            }
        }
        __builtin_amdgcn_s_setprio(0);
        float bi_r = bih[jc], bi_z = bih[HID + jc], bi_n = bih[2 * HID + jc];
        float bh_r = bhh[jc], bh_z = bhh[HID + jc], bh_n = bhh[2 * HID + jc];
#pragma unroll
        for (int tt = 0; tt < 4; ++tt)
#pragma unroll
            for (int q = 0; q < 4; ++q) {
                int row = r0 + tt * 16 + ks * 4 + q;
                float rg = sigm(Ir[tt][q] + bi_r + Hr[tt][q] + bh_r);
                float zg = sigm(Iz[tt][q] + bi_z + Hz[tt][q] + bh_z);
                float ng = ftanh(In[tt][q] + bi_n + rg * (Hn[tt][q] + bh_n));
                float hv = (1.f - zg) * ng + zg * hold[tt][q];
                if (row < NN) h2[(size_t)row * HID + jc] = f2b(hv);
            }
    }
}

// ---------------- standalone wrappers (min 6 waves/EU -> VGPR<=85 -> 3 blocks/CU) ----------------
__global__ __launch_bounds__(512, 6) void gru_step_kernel(const ushort_t* __restrict__ x, ushort_t* __restrict__ h,
                                                          const ushort_t* __restrict__ wih, const ushort_t* __restrict__ whh,
                                                          const float* __restrict__ bih, const float* __restrict__ bhh) {
    gru_body(x, h, wih, whh, bih, bhh, blockIdx.x);
}

__global__ __launch_bounds__(512, 6) void mega2_kernel(const ushort_t* __restrict__ xin2, ushort_t* __restrict__ h2,
                                                       const ushort_t* __restrict__ w1b, const float* __restrict__ b1,
                                                       const float* __restrict__ gg, const float* __restrict__ be,
                                                       const float* __restrict__ rm, const float* __restrict__ rv,
                                                       const ushort_t* __restrict__ w2b, const float* __restrict__ b2,
                                                       const ushort_t* __restrict__ wih, const ushort_t* __restrict__ whh,
                                                       const float* __restrict__ bih, const float* __restrict__ bhh) {
    mega2_body(xin2, h2, w1b, b1, gg, be, rm, rv, w2b, b2, wih, whh, bih, bhh, blockIdx.x);
}

// ---------------- fused: mega2(t) [blocks 0..NBLK) || gru_step(t+1) [blocks NBLK..2*NBLK) ----------------
__global__ __launch_bounds__(512, 6) void fused_mg_kernel(const ushort_t* __restrict__ xin2, ushort_t* __restrict__ h2,
                                                          const ushort_t* __restrict__ w1b, const float* __restrict__ b1,
                                                          const float* __restrict__ gg, const float* __restrict__ be,
                                                          const float* __restrict__ rm, const float* __restrict__ rv,
                                                          const ushort_t* __restrict__ w2b, const float* __restrict__ b2,
                                                          const ushort_t* __restrict__ wih, const ushort_t* __restrict__ whh,
                                                          const float* __restrict__ bih, const float* __restrict__ bhh,
                                                          const ushort_t* __restrict__ emb_next, ushort_t* __restrict__ h1) {
    int b = blockIdx.x;
    if (b < NBLK) {
        mega2_body(xin2, h2, w1b, b1, gg, be, rm, rv, w2b, b2, wih, whh, bih, bhh, b);
    } else {
        gru_body(emb_next, h1, wih, whh, bih, bhh, b - NBLK);
    }
}

// ---------------- conv2 aggregation (128 bf16 features), one wave per node, 4-edge ILP ----------------
__global__ __launch_bounds__(256) void agg128b_kernel(const ushort_t* __restrict__ x,
                                                      const int* __restrict__ rp,
                                                      const int* __restrict__ col,
                                                      ushort_t* __restrict__ out, int E) {
    int node = (blockIdx.x * 256 + threadIdx.x) >> 6;
    int lane = threadIdx.x & 63;
    if (node >= NN) return;
    unsigned v = *(const unsigned*)(x + (size_t)node * HID + lane * 2);
    float s0 = b2f_lo(v);
    float s1 = b2f_hi(v);
    int e0 = rp[node], e1 = rp[node + 1];
    if (e1 > E) e1 = E;
    int e = e0;
    for (; e + 3 < e1; e += 4) {
        unsigned c0 = (unsigned)col[e], c1 = (unsigned)col[e + 1];
        unsigned c2 = (unsigned)col[e + 2], c3 = (unsigned)col[e + 3];
        c0 = (c0 < NN) ? c0 : 0; c1 = (c1 < NN) ? c1 : 0;
        c2 = (c2 < NN) ? c2 : 0; c3 = (c3 < NN) ? c3 : 0;
        unsigned u0 = *(const unsigned*)(x + (size_t)c0 * HID + lane * 2);
        unsigned u1 = *(const unsigned*)(x + (size_t)c1 * HID + lane * 2);
        unsigned u2 = *(const unsigned*)(x + (size_t)c2 * HID + lane * 2);
        unsigned u3 = *(const unsigned*)(x + (size_t)c3 * HID + lane * 2);
        s0 += b2f_lo(u0) + b2f_lo(u1) + b2f_lo(u2) + b2f_lo(u3);
        s1 += b2f_hi(u0) + b2f_hi(u1) + b2f_hi(u2) + b2f_hi(u3);
    }
    for (; e < e1; ++e) {
        unsigned c = (unsigned)col[e];
        if (c < NN) {
            unsigned u = *(const unsigned*)(x + (size_t)c * HID + lane * 2);
            s0 += b2f_lo(u);
            s1 += b2f_hi(u);
        }
    }
    unsigned o = (unsigned)f2b(s0) | ((unsigned)f2b(s1) << 16);
    *(unsigned*)(out + (size_t)node * HID + lane * 2) = o;
}

// ---------------- head ----------------
__global__ __launch_bounds__(64) void head_kernel(const ushort_t* __restrict__ h2, const int* __restrict__ tidx,
                                                  const float* __restrict__ apart,
                                                  const float* __restrict__ w1, const float* __restrict__ b1,
                                                  const float* __restrict__ w2, const float* __restrict__ b2,
                                                  const float* __restrict__ w3, const float* __restrict__ b3,
                                                  float* __restrict__ out) {
    __shared__ float feat[HID + AF_];
    __shared__ float o1[64];
    __shared__ float o2[32];
    int b = blockIdx.x;
    int t = threadIdx.x;
    unsigned node = (unsigned)tidx[b];
    if (node >= NN) node = 0;
    for (int k = t; k < HID; k += 64) feat[k] = b2f(h2[(size_t)node * HID + k]);
    if (t < AF_) feat[HID + t] = apart[(size_t)b * AF_ + t];
    __syncthreads();
    {
        float s = b1[t];
        for (int k = 0; k < HID + AF_; ++k) s += feat[k] * w1[t * (HID + AF_) + k];
        o1[t] = (s > 0.f) ? s : 0.1f * s;
    }
    __syncthreads();
    if (t < 32) {
        float s = b2[t];
        for (int k = 0; k < 64; ++k) s += o1[k] * w2[t * 64 + k];
        o2[t] = (s > 0.f) ? s : 0.05f * s;
    }
    __syncthreads();
    if (t == 0) {
        float s = b3[0];
        for (int k = 0; k < 32; ++k) s += o2[k] * w3[k];
        out[b] = s;
    }
}

extern "C" void kernel_launch(void* const* d_in, const int* in_sizes, int n_in,
                              void* d_out, int out_size, void* d_ws, size_t ws_size,
                              hipStream_t stream) {
    // ---- strict input-mapping validation ----
    int ie_src = -1, ie_dst = -1, ie_tidx = -1, iw0 = -1;
    bool ok = false;
    if (n_in >= 31 && in_sizes[0] == T_STEPS * NN * IN_F && in_sizes[1] == BB * AF_) {
        if (in_sizes[2] > 100000 && in_sizes[3] == in_sizes[2] && in_sizes[4] == BB &&
            in_sizes[5] == HID * IN_F && in_sizes[11] == HID * HID &&
            in_sizes[21] == G3 * HID && in_sizes[22] == G3 * HID &&
            in_sizes[25] == 64 * (HID + AF_)) {
            ie_src = 2; ie_dst = 3; ie_tidx = 4; iw0 = 5; ok = true;
        } else if (in_sizes[2] == HID * IN_F && in_sizes[8] == HID * HID &&
                   in_sizes[18] == G3 * HID && in_sizes[19] == G3 * HID &&
                   in_sizes[22] == 64 * (HID + AF_) &&
                   in_sizes[28] > 100000 && in_sizes[29] == in_sizes[28] && in_sizes[30] == BB) {
            iw0 = 2; ie_src = 28; ie_dst = 29; ie_tidx = 30; ok = true;
        }
    }
    if (!ok) {
        zero_out_kernel<<<(out_size + 255) / 256, 256, 0, stream>>>((float*)d_out, out_size);
        return;
    }

    const float* x_seq  = (const float*)d_in[0];
    const float* apart  = (const float*)d_in[1];
    const int*   e_src  = (const int*)d_in[ie_src];
    const int*   e_dst  = (const int*)d_in[ie_dst];
    const int*   t_idx  = (const int*)d_in[ie_tidx];
    const float* c1_w1 = (const float*)d_in[iw0 + 0];
    const float* c1_b1 = (const float*)d_in[iw0 + 1];
    const float* c1_g  = (const float*)d_in[iw0 + 2];
    const float* c1_be = (const float*)d_in[iw0 + 3];
    const float* c1_rm = (const float*)d_in[iw0 + 4];
    const float* c1_rv = (const float*)d_in[iw0 + 5];
    const float* c1_w2 = (const float*)d_in[iw0 + 6];
    const float* c1_b2 = (const float*)d_in[iw0 + 7];
    const float* c2_w1 = (const float*)d_in[iw0 + 8];
    const float* c2_b1 = (const float*)d_in[iw0 + 9];
    const float* c2_g  = (const float*)d_in[iw0 + 10];
    const float* c2_be = (const float*)d_in[iw0 + 11];
    const float* c2_rm = (const float*)d_in[iw0 + 12];
    const float* c2_rv = (const float*)d_in[iw0 + 13];
    const float* c2_w2 = (const float*)d_in[iw0 + 14];
    const float* c2_b2 = (const float*)d_in[iw0 + 15];
    const float* g_wih = (const float*)d_in[iw0 + 16];
    const float* g_whh = (const float*)d_in[iw0 + 17];
    const float* g_bih = (const float*)d_in[iw0 + 18];
    const float* g_bhh = (const float*)d_in[iw0 + 19];
    const float* f1_w  = (const float*)d_in[iw0 + 20];
    const float* f1_b  = (const float*)d_in[iw0 + 21];
    const float* f2_w  = (const float*)d_in[iw0 + 22];
    const float* f2_b  = (const float*)d_in[iw0 + 23];
    const float* f3_w  = (const float*)d_in[iw0 + 24];
    const float* f3_b  = (const float*)d_in[iw0 + 25];

    int E = in_sizes[ie_src];
    if (E > EE) E = EE;

    // ---- scratch ----
    char* base;
    if (ws_size >= WS_NEED) {
        base = (char*)d_ws;
    } else {
        void* sp = nullptr;
        hipGetSymbolAddress(&sp, HIP_SYMBOL(g_static_pool));
        if (sp == nullptr) {
            zero_out_kernel<<<(out_size + 255) / 256, 256, 0, stream>>>((float*)d_out, out_size);
            return;
        }
        base = (char*)sp;
    }
    size_t off = 0;
    auto nxt = [&](size_t bytes) { char* p = base + off; off += bytes; return p; };
    int*      deg      = (int*)nxt(SZ_DEG);
    int*      row_ptr  = (int*)nxt(SZ_RP);
    int*      cursor   = (int*)nxt(SZ_CUR);
    int*      col      = (int*)nxt(SZ_COL);
    float*    xT       = (float*)nxt(SZ_XT);
    float*    xagg     = (float*)nxt(SZ_XT);
    ushort_t* emb      = (ushort_t*)nxt(SZ_EMB);
    ushort_t* xin2     = (ushort_t*)nxt(SZ_NHB);
    ushort_t* h1       = (ushort_t*)nxt(SZ_NHB);
    ushort_t* h2       = (ushort_t*)nxt(SZ_NHB);
    ushort_t* wb_c1w2  = (ushort_t*)nxt(SZ_W128);
    ushort_t* wb_c2w1  = (ushort_t*)nxt(SZ_W128);
    ushort_t* wb_c2w2  = (ushort_t*)nxt(SZ_W128);
    ushort_t* wb_wih   = (ushort_t*)nxt(SZ_WGRU);
    ushort_t* wb_whh   = (ushort_t*)nxt(SZ_WGRU);

    const int NW = 3 * HID * HID + 2 * G3 * HID;
    cvt5_kernel<<<(NW + 255) / 256, 256, 0, stream>>>(c1_w2, wb_c1w2, HID * HID,
                                                      c2_w1, wb_c2w1, HID * HID,
                                                      c2_w2, wb_c2w2, HID * HID,
                                                      g_wih, wb_wih, G3 * HID,
                                                      g_whh, wb_whh, G3 * HID);

    init_kernel<<<(NN * HID + 255) / 256, 256, 0, stream>>>(deg, h1, h2);

    hist_kernel<<<(E + 255) / 256, 256, 0, stream>>>(e_dst, deg, E);
    scan_kernel<<<1, 1024, 0, stream>>>(deg, row_ptr, cursor, NN);
    scatter_kernel<<<(E + 255) / 256, 256, 0, stream>>>(e_src, e_dst, cursor, col, E);

    // conv1 for all timesteps: transpose -> single-pass all-plane gather -> compute
    transpose_x_kernel<<<(NN * TF12 + 255) / 256, 256, 0, stream>>>(x_seq, xT);
    agg12t_kernel<<<(NN + 7) / 8, 512, 0, stream>>>(xT, row_ptr, col, xagg, E);
    conv1c_all_kernel<<<dim3(NBLK, T_STEPS), 512, 0, stream>>>(xagg, emb,
                                                               c1_w1, c1_b1, c1_g, c1_be, c1_rm, c1_rv,
                                                               wb_c1w2, c1_b2);

    // t = 0 prologue
    gru_step_kernel<<<NBLK, 512, 0, stream>>>(emb, h1, wb_wih, wb_whh, g_bih, g_bhh);
    agg128b_kernel<<<(NN * 64 + 255) / 256, 256, 0, stream>>>(h1, row_ptr, col, xin2, E);
    // fused steady state: mega2(t) || gru_step(t+1), then agg(t+1)
    for (int t = 0; t < T_STEPS - 1; ++t) {
        fused_mg_kernel<<<2 * NBLK, 512, 0, stream>>>(xin2, h2,
                                                      wb_c2w1, c2_b1, c2_g, c2_be, c2_rm, c2_rv,
                                                      wb_c2w2, c2_b2,
                                                      wb_wih, wb_whh, g_bih, g_bhh,
                                                      emb + (size_t)(t + 1) * NN * HID, h1);
        agg128b_kernel<<<(NN * 64 + 255) / 256, 256, 0, stream>>>(h1, row_ptr, col, xin2, E);
    }
    // t = T-1 epilogue
    mega2_kernel<<<NBLK, 512, 0, stream>>>(xin2, h2,
                                           wb_c2w1, c2_b1, c2_g, c2_be, c2_rm, c2_rv,
                                           wb_c2w2, c2_b2,
                                           wb_wih, wb_whh, g_bih, g_bhh);

    head_kernel<<<BB, 64, 0, stream>>>(h2, t_idx, apart, f1_w, f1_b, f2_w, f2_b, f3_w, f3_b, (float*)d_out);
}

// Round 17
// 2258.382 us; speedup vs baseline: 2.3537x; 2.3537x over previous
//
#include <hip/hip_runtime.h>

#define T_STEPS 12
#define NN      50000
#define EE      800000
#define IN_F    12
#define TF12    (T_STEPS * IN_F)
#define HID     128
#define G3      384
#define BB      4096
#define AF_     10
#define BN_EPS  1e-5f
#define LPAD    136
#define NBLK    ((NN + 63) / 64)

typedef unsigned short ushort_t;
typedef __attribute__((ext_vector_type(8))) short bf16x8;
typedef __attribute__((ext_vector_type(4))) float f32x4;

#define MFMA(a, b, c) __builtin_amdgcn_mfma_f32_16x16x32_bf16((a), (b), (c), 0, 0, 0)
#define L2E 1.4426950408889634f

__device__ inline float b2f(ushort_t u) { return __uint_as_float(((unsigned)u) << 16); }
__device__ inline float b2f_lo(unsigned u) { return __uint_as_float(u << 16); }
__device__ inline float b2f_hi(unsigned u) { return __uint_as_float(u & 0xffff0000u); }
__device__ inline ushort_t f2b(float f) {
    unsigned u = __float_as_uint(f);
    return (ushort_t)((u + 0x7fffu + ((u >> 16) & 1u)) >> 16);
}
__device__ inline float sigm(float x) {
    return __builtin_amdgcn_rcpf(1.f + __builtin_amdgcn_exp2f(-x * L2E));
}
__device__ inline float ftanh(float x) {
    float xx = fminf(fmaxf(x, -15.f), 15.f);
    float t = __builtin_amdgcn_exp2f(2.f * L2E * xx);
    return (t - 1.f) * __builtin_amdgcn_rcpf(t + 1.f);
}

#define ALIGN_UP(x) (((x) + 255) & ~(size_t)255)
#define SZ_DEG    ALIGN_UP((size_t)NN * 4)
#define SZ_RP     ALIGN_UP((size_t)(NN + 1) * 4)
#define SZ_CUR    ALIGN_UP((size_t)NN * 4)
#define SZ_COL    ALIGN_UP((size_t)EE * 4)
#define SZ_XT     ALIGN_UP((size_t)NN * TF12 * 4)
#define SZ_EMB    ALIGN_UP((size_t)T_STEPS * NN * HID * 2)
#define SZ_NHB    ALIGN_UP((size_t)NN * HID * 2)
#define SZ_W128   ALIGN_UP((size_t)HID * HID * 2)
#define SZ_WGRU   ALIGN_UP((size_t)G3 * HID * 2)
#define WS_NEED   (SZ_DEG + SZ_RP + SZ_CUR + SZ_COL + 2 * SZ_XT + SZ_EMB + 3 * SZ_NHB + 3 * SZ_W128 + 2 * SZ_WGRU)

__device__ __align__(256) char g_static_pool[WS_NEED];

// ---------------- bail path ----------------
__global__ void zero_out_kernel(float* out, int n) {
    int i = blockIdx.x * blockDim.x + threadIdx.x;
    if (i < n) out[i] = 0.f;
}

// ---------------- weights fp32 -> bf16 ----------------
__global__ void cvt5_kernel(const float* s0, ushort_t* d0, int n0,
                            const float* s1, ushort_t* d1, int n1,
                            const float* s2, ushort_t* d2, int n2,
                            const float* s3, ushort_t* d3, int n3,
                            const float* s4, ushort_t* d4, int n4) {
    int i = blockIdx.x * blockDim.x + threadIdx.x;
    if (i < n0) d0[i] = f2b(s0[i]);
    i -= n0;
    if (i >= 0 && i < n1) d1[i] = f2b(s1[i]);
    i -= n1;
    if (i >= 0 && i < n2) d2[i] = f2b(s2[i]);
    i -= n2;
    if (i >= 0 && i < n3) d3[i] = f2b(s3[i]);
    i -= n3;
    if (i >= 0 && i < n4) d4[i] = f2b(s4[i]);
}

// ---------------- init ----------------
__global__ void init_kernel(int* deg, ushort_t* h1, ushort_t* h2) {
    int i = blockIdx.x * blockDim.x + threadIdx.x;
    if (i < NN) deg[i] = 0;
    if (i < NN * HID) { h1[i] = 0; h2[i] = 0; }
}

// ---------------- CSR build ----------------
__global__ void hist_kernel(const int* __restrict__ dst, int* __restrict__ deg, int E) {
    int e = blockIdx.x * blockDim.x + threadIdx.x;
    if (e < E) {
        unsigned d = (unsigned)dst[e];
        if (d < NN) atomicAdd(&deg[d], 1);
    }
}

__global__ __launch_bounds__(1024) void scan_kernel(const int* __restrict__ deg,
                                                    int* __restrict__ row_ptr,
                                                    int* __restrict__ cursor, int n) {
    __shared__ int wsum[16];
    __shared__ int carry_s;
    int tid = threadIdx.x;
    int wid = tid >> 6, lane = tid & 63;
    if (tid == 0) { carry_s = 0; row_ptr[0] = 0; }
    __syncthreads();
    for (int base = 0; base < n; base += 1024) {
        int i = base + tid;
        int v = (i < n) ? deg[i] : 0;
        int x = v;
#pragma unroll
        for (int off = 1; off < 64; off <<= 1) {
            int t = __shfl_up(x, (unsigned)off);
            if (lane >= off) x += t;
        }
        if (lane == 63) wsum[wid] = x;
        __syncthreads();
        if (tid == 0) {
            int a = 0;
#pragma unroll
            for (int w = 0; w < 16; ++w) { int t = wsum[w]; wsum[w] = a; a += t; }
        }
        __syncthreads();
        int incl = carry_s + wsum[wid] + x;
        if (i < n) {
            row_ptr[i + 1] = incl;
            cursor[i] = incl - v;
        }
        __syncthreads();
        if (tid == 1023) carry_s = incl;
        __syncthreads();
    }
}

__global__ void scatter_kernel(const int* __restrict__ src, const int* __restrict__ dst,
                               int* __restrict__ cursor, int* __restrict__ col, int E) {
    int e = blockIdx.x * blockDim.x + threadIdx.x;
    if (e < E) {
        unsigned d = (unsigned)dst[e];
        if (d < NN) {
            int pos = atomicAdd(&cursor[d], 1);
            if ((unsigned)pos < (unsigned)EE) col[pos] = src[e];
        }
    }
}

// ---------------- transpose x: xT[n][t*12+f] = x[t][n][f] ----------------
__global__ void transpose_x_kernel(const float* __restrict__ x_seq, float* __restrict__ xT) {
    int g = blockIdx.x * blockDim.x + threadIdx.x;
    if (g >= NN * TF12) return;
    int n = g / TF12;
    int u = g - n * TF12;
    int t = u / IN_F;
    int f = u - t * IN_F;
    xT[g] = x_seq[(size_t)t * NN * IN_F + (size_t)n * IN_F + f];
}

// ---------------- agg12t: wave per node, ALL 12 planes in ONE edge-walk ----------------
__global__ __launch_bounds__(512) void agg12t_kernel(const float* __restrict__ xT,
                                                     const int* __restrict__ rp,
                                                     const int* __restrict__ col,
                                                     float* __restrict__ xagg, int E) {
    int node = blockIdx.x * 8 + (threadIdx.x >> 6);
    int lane = threadIdx.x & 63;
    if (node >= NN) return;
    const float2* pself = (const float2*)(xT + (size_t)node * TF12);
    float2 a = pself[lane];
    float a2 = (lane < 16) ? xT[(size_t)node * TF12 + 128 + lane] : 0.f;
    int e0 = rp[node], e1 = rp[node + 1];
    if (e1 > E) e1 = E;
    int e = e0;
    for (; e + 1 < e1; e += 2) {
        unsigned c0 = (unsigned)col[e], c1 = (unsigned)col[e + 1];
        c0 = (c0 < NN) ? c0 : 0; c1 = (c1 < NN) ? c1 : 0;
        const float2* p0 = (const float2*)(xT + (size_t)c0 * TF12);
        const float2* p1 = (const float2*)(xT + (size_t)c1 * TF12);
        float2 v0 = p0[lane];
        float2 v1 = p1[lane];
        a.x += v0.x + v1.x;
        a.y += v0.y + v1.y;
        if (lane < 16)
            a2 += xT[(size_t)c0 * TF12 + 128 + lane] + xT[(size_t)c1 * TF12 + 128 + lane];
    }
    for (; e < e1; ++e) {
        unsigned c = (unsigned)col[e];
        if (c < NN) {
            const float2* pn = (const float2*)(xT + (size_t)c * TF12);
            float2 v = pn[lane];
            a.x += v.x;
            a.y += v.y;
            if (lane < 16) a2 += xT[(size_t)c * TF12 + 128 + lane];
        }
    }
    ((float2*)(xagg + (size_t)node * TF12))[lane] = a;
    if (lane < 16) xagg[(size_t)node * TF12 + 128 + lane] = a2;
}

// ---------------- conv1 compute for ALL timesteps (input: transposed aggregate) ----------------
__global__ __launch_bounds__(512) void conv1c_all_kernel(const float* __restrict__ xagg,
                                                         ushort_t* __restrict__ emb,
                                                         const float* __restrict__ W1, const float* __restrict__ b1,
                                                         const float* __restrict__ gg, const float* __restrict__ be,
                                                         const float* __restrict__ rm, const float* __restrict__ rv,
                                                         const ushort_t* __restrict__ w2b, const float* __restrict__ b2) {
    __shared__ float xs[64][IN_F + 1];
    __shared__ ushort_t l1[64][LPAD];
    int t = blockIdx.y;
    ushort_t* et = emb + (size_t)t * NN * HID;
    int tid = threadIdx.x;
    int r0 = blockIdx.x * 64;
    for (int u = tid; u < 64 * IN_F; u += 512) {
        int r = u / IN_F, f = u - r * IN_F;
        int row = r0 + r;
        xs[r][f] = (row < NN) ? xagg[(size_t)row * TF12 + t * IN_F + f] : 0.f;
    }
    __syncthreads();
    {
        int j = tid & 127, rb = tid >> 7;
        float sc = gg[j] * rsqrtf(rv[j] + BN_EPS);
        float sh = be[j] - rm[j] * sc;
        float bj = b1[j];
        float wreg[IN_F];
#pragma unroll
        for (int k = 0; k < IN_F; ++k) wreg[k] = W1[j * IN_F + k];
#pragma unroll
        for (int q = 0; q < 16; ++q) {
            int r = rb + q * 4;
            float s = bj;
#pragma unroll
            for (int k = 0; k < IN_F; ++k) s += xs[r][k] * wreg[k];
            s = fmaxf(s, 0.f);
            l1[r][j] = f2b(s * sc + sh);
        }
    }
    __syncthreads();
    {
        int wave = tid >> 6, lane = tid & 63, li = lane & 15, ks = lane >> 4;
        int jc = wave * 16 + li;
        const ushort_t* pw = w2b + (size_t)jc * HID + ks * 8;
        f32x4 A0 = {0,0,0,0}, A1 = {0,0,0,0}, A2 = {0,0,0,0}, A3 = {0,0,0,0};
#pragma unroll
        for (int k0 = 0; k0 < HID; k0 += 32) {
            bf16x8 wf = *(const bf16x8*)(pw + k0);
            bf16x8 a0 = *(const bf16x8*)&l1[li][ks * 8 + k0];
            bf16x8 a1 = *(const bf16x8*)&l1[li + 16][ks * 8 + k0];
            bf16x8 a2 = *(const bf16x8*)&l1[li + 32][ks * 8 + k0];
            bf16x8 a3 = *(const bf16x8*)&l1[li + 48][ks * 8 + k0];
            A0 = MFMA(a0, wf, A0); A1 = MFMA(a1, wf, A1);
            A2 = MFMA(a2, wf, A2); A3 = MFMA(a3, wf, A3);
        }
        float bj = b2[jc];
#pragma unroll
        for (int q = 0; q < 4; ++q) {
            int rA = r0 + ks * 4 + q, rB = rA + 16, rC = rA + 32, rD = rA + 48;
            if (rA < NN) et[(size_t)rA * HID + jc] = f2b(fmaxf(A0[q] + bj, 0.f));
            if (rB < NN) et[(size_t)rB * HID + jc] = f2b(fmaxf(A1[q] + bj, 0.f));
            if (rC < NN) et[(size_t)rC * HID + jc] = f2b(fmaxf(A2[q] + bj, 0.f));
            if (rD < NN) et[(size_t)rD * HID + jc] = f2b(fmaxf(A3[q] + bj, 0.f));
        }
    }
}

// ---------------- GRU body: h(rows blk*64..+64) <- GRU(x, h), in place ----------------
__device__ __forceinline__ void gru_body(const ushort_t* __restrict__ x,
                                         ushort_t* __restrict__ h,
                                         const ushort_t* __restrict__ wih,
                                         const ushort_t* __restrict__ whh,
                                         const float* __restrict__ bih,
                                         const float* __restrict__ bhh, int blk) {
    int tid = threadIdx.x;
    int wave = tid >> 6, lane = tid & 63, li = lane & 15, ks = lane >> 4;
    int r0 = blk * 64;
    int jc = wave * 16 + li;
    const ushort_t* px[4];
    const ushort_t* ph[4];
#pragma unroll
    for (int tt = 0; tt < 4; ++tt) {
        int ra = min(r0 + tt * 16 + li, NN - 1);
        px[tt] = x + (size_t)ra * HID + ks * 8;
        ph[tt] = h + (size_t)ra * HID + ks * 8;
    }
    const ushort_t* pwr = wih + (size_t)jc * HID + ks * 8;
    const ushort_t* pwz = wih + (size_t)(HID + jc) * HID + ks * 8;
    const ushort_t* pwn = wih + (size_t)(2 * HID + jc) * HID + ks * 8;
    const ushort_t* pvr = whh + (size_t)jc * HID + ks * 8;
    const ushort_t* pvz = whh + (size_t)(HID + jc) * HID + ks * 8;
    const ushort_t* pvn = whh + (size_t)(2 * HID + jc) * HID + ks * 8;
    f32x4 Ir[4], Iz[4], In[4], Hr[4], Hz[4], Hn[4];
#pragma unroll
    for (int tt = 0; tt < 4; ++tt) {
        Ir[tt] = (f32x4){0,0,0,0}; Iz[tt] = (f32x4){0,0,0,0}; In[tt] = (f32x4){0,0,0,0};
        Hr[tt] = (f32x4){0,0,0,0}; Hz[tt] = (f32x4){0,0,0,0}; Hn[tt] = (f32x4){0,0,0,0};
    }
    __builtin_amdgcn_s_setprio(1);
#pragma unroll
    for (int k0 = 0; k0 < HID; k0 += 32) {
        bf16x8 wr = *(const bf16x8*)(pwr + k0);
        bf16x8 wz = *(const bf16x8*)(pwz + k0);
        bf16x8 wn = *(const bf16x8*)(pwn + k0);
        bf16x8 vr = *(const bf16x8*)(pvr + k0);
        bf16x8 vz = *(const bf16x8*)(pvz + k0);
        bf16x8 vn = *(const bf16x8*)(pvn + k0);
#pragma unroll
        for (int tt = 0; tt < 4; ++tt) {
            bf16x8 xf = *(const bf16x8*)(px[tt] + k0);
            bf16x8 hf = *(const bf16x8*)(ph[tt] + k0);
            Ir[tt] = MFMA(xf, wr, Ir[tt]);
            Iz[tt] = MFMA(xf, wz, Iz[tt]);
            In[tt] = MFMA(xf, wn, In[tt]);
            Hr[tt] = MFMA(hf, vr, Hr[tt]);
            Hz[tt] = MFMA(hf, vz, Hz[tt]);
            Hn[tt] = MFMA(hf, vn, Hn[tt]);
        }
    }
    __builtin_amdgcn_s_setprio(0);
    float bi_r = bih[jc], bi_z = bih[HID + jc], bi_n = bih[2 * HID + jc];
    float bh_r = bhh[jc], bh_z = bhh[HID + jc], bh_n = bhh[2 * HID + jc];
    float hold[4][4];
#pragma unroll
    for (int tt = 0; tt < 4; ++tt)
#pragma unroll
        for (int q = 0; q < 4; ++q) {
            int rr = min(r0 + tt * 16 + ks * 4 + q, NN - 1);
            hold[tt][q] = b2f(h[(size_t)rr * HID + jc]);
        }
    __syncthreads();  // all block-wide reads of h complete before in-place writes
#pragma unroll
    for (int tt = 0; tt < 4; ++tt)
#pragma unroll
        for (int q = 0; q < 4; ++q) {
            int row = r0 + tt * 16 + ks * 4 + q;
            float rg = sigm(Ir[tt][q] + bi_r + Hr[tt][q] + bh_r);
            float zg = sigm(Iz[tt][q] + bi_z + Hz[tt][q] + bh_z);
            float ng = ftanh(In[tt][q] + bi_n + rg * (Hn[tt][q] + bh_n));
            float hv = (1.f - zg) * ng + zg * hold[tt][q];
            if (row < NN) h[(size_t)row * HID + jc] = f2b(hv);
        }
}

// ---------------- mega2 body: conv2-l1 (+h-side GRU overlap) -> l2 -> GRU2, rows blk*64..+64 ----------------
__device__ __forceinline__ void mega2_body(const ushort_t* __restrict__ xin2,
                                           ushort_t* __restrict__ h2,
                                           const ushort_t* __restrict__ w1b, const float* __restrict__ b1,
                                           const float* __restrict__ gg, const float* __restrict__ be,
                                           const float* __restrict__ rm, const float* __restrict__ rv,
                                           const ushort_t* __restrict__ w2b, const float* __restrict__ b2,
                                           const ushort_t* __restrict__ wih, const ushort_t* __restrict__ whh,
                                           const float* __restrict__ bih, const float* __restrict__ bhh, int blk) {
    __shared__ ushort_t bufA[64][LPAD];
    __shared__ ushort_t bufB[64][LPAD];
    int tid = threadIdx.x;
    int wave = tid >> 6, lane = tid & 63, li = lane & 15, ks = lane >> 4;
    int r0 = blk * 64;
    int jc = wave * 16 + li;
    f32x4 Hr[4], Hz[4], Hn[4], C1[4];
#pragma unroll
    for (int tt = 0; tt < 4; ++tt) {
        Hr[tt] = (f32x4){0,0,0,0}; Hz[tt] = (f32x4){0,0,0,0};
        Hn[tt] = (f32x4){0,0,0,0}; C1[tt] = (f32x4){0,0,0,0};
    }
    {
        const ushort_t* pw1 = w1b + (size_t)jc * HID + ks * 8;
        const ushort_t* pvr = whh + (size_t)jc * HID + ks * 8;
        const ushort_t* pvz = whh + (size_t)(HID + jc) * HID + ks * 8;
        const ushort_t* pvn = whh + (size_t)(2 * HID + jc) * HID + ks * 8;
        const ushort_t* pa[4];
        const ushort_t* ph[4];
#pragma unroll
        for (int tt = 0; tt < 4; ++tt) {
            int ra = min(r0 + tt * 16 + li, NN - 1);
            pa[tt] = xin2 + (size_t)ra * HID + ks * 8;
            ph[tt] = h2 + (size_t)ra * HID + ks * 8;
        }
        __builtin_amdgcn_s_setprio(1);
#pragma unroll
        for (int k0 = 0; k0 < HID; k0 += 32) {
            bf16x8 w1f = *(const bf16x8*)(pw1 + k0);
            bf16x8 vr = *(const bf16x8*)(pvr + k0);
            bf16x8 vz = *(const bf16x8*)(pvz + k0);
            bf16x8 vn = *(const bf16x8*)(pvn + k0);
#pragma unroll
            for (int tt = 0; tt < 4; ++tt) {
                bf16x8 af = *(const bf16x8*)(pa[tt] + k0);
                bf16x8 hf = *(const bf16x8*)(ph[tt] + k0);
                C1[tt] = MFMA(af, w1f, C1[tt]);
                Hr[tt] = MFMA(hf, vr, Hr[tt]);
                Hz[tt] = MFMA(hf, vz, Hz[tt]);
                Hn[tt] = MFMA(hf, vn, Hn[tt]);
            }
        }
        __builtin_amdgcn_s_setprio(0);
    }
    float hold[4][4];
#pragma unroll
    for (int tt = 0; tt < 4; ++tt)
#pragma unroll
        for (int q = 0; q < 4; ++q) {
            int rr = min(r0 + tt * 16 + ks * 4 + q, NN - 1);
            hold[tt][q] = b2f(h2[(size_t)rr * HID + jc]);
        }
    {
        float sc = gg[jc] * rsqrtf(rv[jc] + BN_EPS);
        float sh = be[jc] - rm[jc] * sc;
        float bj = b1[jc];
#pragma unroll
        for (int tt = 0; tt < 4; ++tt)
#pragma unroll
            for (int q = 0; q < 4; ++q)
                bufB[tt * 16 + ks * 4 + q][jc] = f2b(fmaxf(C1[tt][q] + bj, 0.f) * sc + sh);
    }
    __syncthreads();
    {
        const ushort_t* pw2 = w2b + (size_t)jc * HID + ks * 8;
        f32x4 C2[4];
#pragma unroll
        for (int tt = 0; tt < 4; ++tt) C2[tt] = (f32x4){0,0,0,0};
        __builtin_amdgcn_s_setprio(1);
#pragma unroll
        for (int k0 = 0; k0 < HID; k0 += 32) {
            bf16x8 wf = *(const bf16x8*)(pw2 + k0);
#pragma unroll
            for (int tt = 0; tt < 4; ++tt) {
                bf16x8 af = *(const bf16x8*)&bufB[li + 16 * tt][ks * 8 + k0];
                C2[tt] = MFMA(af, wf, C2[tt]);
            }
        }
        __builtin_amdgcn_s_setprio(0);
        float bj = b2[jc];
#pragma unroll
        for (int tt = 0; tt < 4; ++tt)
#pragma unroll
            for (int q = 0; q < 4; ++q)
                bufA[tt * 16 + ks * 4 + q][jc] = f2b(fmaxf(C2[tt][q] + bj, 0.f));
    }
    __syncthreads();
    {
        const ushort_t* pwr = wih + (size_t)jc * HID + ks * 8;
        const ushort_t* pwz = wih + (size_t)(HID + jc) * HID + ks * 8;
        const ushort_t* pwn = wih + (size_t)(2 * HID + jc) * HID + ks * 8;
        f32x4 Ir[4], Iz[4], In[4];
#pragma unroll
        for (int tt = 0; tt < 4; ++tt) {
            Ir[tt] = (f32x4){0,0,0,0}; Iz[tt] = (f32x4){0,0,0,0}; In[tt] = (f32x4){0,0,0,0};
        }
        __builtin_amdgcn_s_setprio(1);
#pragma unroll
        for (int k0 = 0; k0 < HID; k0 += 32) {
            bf16x8 wr = *(const bf16x8*)(pwr + k0);
            bf16x8 wz = *(const bf16x8*)(pwz + k0);
            bf16x8 wn = *(const bf16x8*)(pwn + k0);
#pragma unroll
            for (int tt = 0; tt < 4; ++tt) {
                bf16x8 xf = *(const bf16x8*)&bufA[li + 16 * tt][ks * 8 + k0];
                Ir[tt] = MFMA(xf, wr, Ir[tt]);
                Iz[tt] = MFMA(xf, wz, Iz[tt]);
                In[tt] = MFMA(xf, wn, In[tt]);
            }
        }
        __builtin_amdgcn_s_setprio(0);
        float bi_r = bih[jc], bi_z = bih[HID + jc], bi_n = bih[2 * HID + jc];
        float bh_r = bhh[jc], bh_z = bhh[HID + jc], bh_n = bhh[2 * HID + jc];
#pragma unroll
        for (int tt = 0; tt < 4; ++tt)
#pragma unroll
            for (int q = 0; q < 4; ++q) {
                int row = r0 + tt * 16 + ks * 4 + q;
                float rg = sigm(Ir[tt][q] + bi_r + Hr[tt][q] + bh_r);
                float zg = sigm(Iz[tt][q] + bi_z + Hz[tt][q] + bh_z);
                float ng = ftanh(In[tt][q] + bi_n + rg * (Hn[tt][q] + bh_n));
                float hv = (1.f - zg) * ng + zg * hold[tt][q];
                if (row < NN) h2[(size_t)row * HID + jc] = f2b(hv);
            }
    }
}

// ---------------- standalone wrappers ----------------
__global__ __launch_bounds__(512) void gru_step_kernel(const ushort_t* __restrict__ x, ushort_t* __restrict__ h,
                                                       const ushort_t* __restrict__ wih, const ushort_t* __restrict__ whh,
                                                       const float* __restrict__ bih, const float* __restrict__ bhh) {
    gru_body(x, h, wih, whh, bih, bhh, blockIdx.x);
}

__global__ __launch_bounds__(512) void mega2_kernel(const ushort_t* __restrict__ xin2, ushort_t* __restrict__ h2,
                                                    const ushort_t* __restrict__ w1b, const float* __restrict__ b1,
                                                    const float* __restrict__ gg, const float* __restrict__ be,
                                                    const float* __restrict__ rm, const float* __restrict__ rv,
                                                    const ushort_t* __restrict__ w2b, const float* __restrict__ b2,
                                                    const ushort_t* __restrict__ wih, const ushort_t* __restrict__ whh,
                                                    const float* __restrict__ bih, const float* __restrict__ bhh) {
    mega2_body(xin2, h2, w1b, b1, gg, be, rm, rv, w2b, b2, wih, whh, bih, bhh, blockIdx.x);
}

// ---------------- fused: mega2(t) [blocks 0..NBLK) || gru_step(t+1) [blocks NBLK..2*NBLK) ----------------
__global__ __launch_bounds__(512) void fused_mg_kernel(const ushort_t* __restrict__ xin2, ushort_t* __restrict__ h2,
                                                       const ushort_t* __restrict__ w1b, const float* __restrict__ b1,
                                                       const float* __restrict__ gg, const float* __restrict__ be,
                                                       const float* __restrict__ rm, const float* __restrict__ rv,
                                                       const ushort_t* __restrict__ w2b, const float* __restrict__ b2,
                                                       const ushort_t* __restrict__ wih, const ushort_t* __restrict__ whh,
                                                       const float* __restrict__ bih, const float* __restrict__ bhh,
                                                       const ushort_t* __restrict__ emb_next, ushort_t* __restrict__ h1) {
    int b = blockIdx.x;
    if (b < NBLK) {
        mega2_body(xin2, h2, w1b, b1, gg, be, rm, rv, w2b, b2, wih, whh, bih, bhh, b);
    } else {
        gru_body(emb_next, h1, wih, whh, bih, bhh, b - NBLK);
    }
}

// ---------------- conv2 aggregation (128 bf16 features), one wave per node, 4-edge ILP ----------------
__global__ __launch_bounds__(256) void agg128b_kernel(const ushort_t* __restrict__ x,
                                                      const int* __restrict__ rp,
                                                      const int* __restrict__ col,
                                                      ushort_t* __restrict__ out, int E) {
    int node = (blockIdx.x * 256 + threadIdx.x) >> 6;
    int lane = threadIdx.x & 63;
    if (node >= NN) return;
    unsigned v = *(const unsigned*)(x + (size_t)node * HID + lane * 2);
    float s0 = b2f_lo(v);
    float s1 = b2f_hi(v);
    int e0 = rp[node], e1 = rp[node + 1];
    if (e1 > E) e1 = E;
    int e = e0;
    for (; e + 3 < e1; e += 4) {
        unsigned c0 = (unsigned)col[e], c1 = (unsigned)col[e + 1];
        unsigned c2 = (unsigned)col[e + 2], c3 = (unsigned)col[e + 3];
        c0 = (c0 < NN) ? c0 : 0; c1 = (c1 < NN) ? c1 : 0;
        c2 = (c2 < NN) ? c2 : 0; c3 = (c3 < NN) ? c3 : 0;
        unsigned u0 = *(const unsigned*)(x + (size_t)c0 * HID + lane * 2);
        unsigned u1 = *(const unsigned*)(x + (size_t)c1 * HID + lane * 2);
        unsigned u2 = *(const unsigned*)(x + (size_t)c2 * HID + lane * 2);
        unsigned u3 = *(const unsigned*)(x + (size_t)c3 * HID + lane * 2);
        s0 += b2f_lo(u0) + b2f_lo(u1) + b2f_lo(u2) + b2f_lo(u3);
        s1 += b2f_hi(u0) + b2f_hi(u1) + b2f_hi(u2) + b2f_hi(u3);
    }
    for (; e < e1; ++e) {
        unsigned c = (unsigned)col[e];
        if (c < NN) {
            unsigned u = *(const unsigned*)(x + (size_t)c * HID + lane * 2);
            s0 += b2f_lo(u);
            s1 += b2f_hi(u);
        }
    }
    unsigned o = (unsigned)f2b(s0) | ((unsigned)f2b(s1) << 16);
    *(unsigned*)(out + (size_t)node * HID + lane * 2) = o;
}

// ---------------- head ----------------
__global__ __launch_bounds__(64) void head_kernel(const ushort_t* __restrict__ h2, const int* __restrict__ tidx,
                                                  const float* __restrict__ apart,
                                                  const float* __restrict__ w1, const float* __restrict__ b1,
                                                  const float* __restrict__ w2, const float* __restrict__ b2,
                                                  const float* __restrict__ w3, const float* __restrict__ b3,
                                                  float* __restrict__ out) {
    __shared__ float feat[HID + AF_];
    __shared__ float o1[64];
    __shared__ float o2[32];
    int b = blockIdx.x;
    int t = threadIdx.x;
    unsigned node = (unsigned)tidx[b];
    if (node >= NN) node = 0;
    for (int k = t; k < HID; k += 64) feat[k] = b2f(h2[(size_t)node * HID + k]);
    if (t < AF_) feat[HID + t] = apart[(size_t)b * AF_ + t];
    __syncthreads();
    {
        float s = b1[t];
        for (int k = 0; k < HID + AF_; ++k) s += feat[k] * w1[t * (HID + AF_) + k];
        o1[t] = (s > 0.f) ? s : 0.1f * s;
    }
    __syncthreads();
    if (t < 32) {
        float s = b2[t];
        for (int k = 0; k < 64; ++k) s += o1[k] * w2[t * 64 + k];
        o2[t] = (s > 0.f) ? s : 0.05f * s;
    }
    __syncthreads();
    if (t == 0) {
        float s = b3[0];
        for (int k = 0; k < 32; ++k) s += o2[k] * w3[k];
        out[b] = s;
    }
}

extern "C" void kernel_launch(void* const* d_in, const int* in_sizes, int n_in,
                              void* d_out, int out_size, void* d_ws, size_t ws_size,
                              hipStream_t stream) {
    // ---- strict input-mapping validation ----
    int ie_src = -1, ie_dst = -1, ie_tidx = -1, iw0 = -1;
    bool ok = false;
    if (n_in >= 31 && in_sizes[0] == T_STEPS * NN * IN_F && in_sizes[1] == BB * AF_) {
        if (in_sizes[2] > 100000 && in_sizes[3] == in_sizes[2] && in_sizes[4] == BB &&
            in_sizes[5] == HID * IN_F && in_sizes[11] == HID * HID &&
            in_sizes[21] == G3 * HID && in_sizes[22] == G3 * HID &&
            in_sizes[25] == 64 * (HID + AF_)) {
            ie_src = 2; ie_dst = 3; ie_tidx = 4; iw0 = 5; ok = true;
        } else if (in_sizes[2] == HID * IN_F && in_sizes[8] == HID * HID &&
                   in_sizes[18] == G3 * HID && in_sizes[19] == G3 * HID &&
                   in_sizes[22] == 64 * (HID + AF_) &&
                   in_sizes[28] > 100000 && in_sizes[29] == in_sizes[28] && in_sizes[30] == BB) {
            iw0 = 2; ie_src = 28; ie_dst = 29; ie_tidx = 30; ok = true;
        }
    }
    if (!ok) {
        zero_out_kernel<<<(out_size + 255) / 256, 256, 0, stream>>>((float*)d_out, out_size);
        return;
    }

    const float* x_seq  = (const float*)d_in[0];
    const float* apart  = (const float*)d_in[1];
    const int*   e_src  = (const int*)d_in[ie_src];
    const int*   e_dst  = (const int*)d_in[ie_dst];
    const int*   t_idx  = (const int*)d_in[ie_tidx];
    const float* c1_w1 = (const float*)d_in[iw0 + 0];
    const float* c1_b1 = (const float*)d_in[iw0 + 1];
    const float* c1_g  = (const float*)d_in[iw0 + 2];
    const float* c1_be = (const float*)d_in[iw0 + 3];
    const float* c1_rm = (const float*)d_in[iw0 + 4];
    const float* c1_rv = (const float*)d_in[iw0 + 5];
    const float* c1_w2 = (const float*)d_in[iw0 + 6];
    const float* c1_b2 = (const float*)d_in[iw0 + 7];
    const float* c2_w1 = (const float*)d_in[iw0 + 8];
    const float* c2_b1 = (const float*)d_in[iw0 + 9];
    const float* c2_g  = (const float*)d_in[iw0 + 10];
    const float* c2_be = (const float*)d_in[iw0 + 11];
    const float* c2_rm = (const float*)d_in[iw0 + 12];
    const float* c2_rv = (const float*)d_in[iw0 + 13];
    const float* c2_w2 = (const float*)d_in[iw0 + 14];
    const float* c2_b2 = (const float*)d_in[iw0 + 15];
    const float* g_wih = (const float*)d_in[iw0 + 16];
    const float* g_whh = (const float*)d_in[iw0 + 17];
    const float* g_bih = (const float*)d_in[iw0 + 18];
    const float* g_bhh = (const float*)d_in[iw0 + 19];
    const float* f1_w  = (const float*)d_in[iw0 + 20];
    const float* f1_b  = (const float*)d_in[iw0 + 21];
    const float* f2_w  = (const float*)d_in[iw0 + 22];
    const float* f2_b  = (const float*)d_in[iw0 + 23];
    const float* f3_w  = (const float*)d_in[iw0 + 24];
    const float* f3_b  = (const float*)d_in[iw0 + 25];

    int E = in_sizes[ie_src];
    if (E > EE) E = EE;

    // ---- scratch ----
    char* base;
    if (ws_size >= WS_NEED) {
        base = (char*)d_ws;
    } else {
        void* sp = nullptr;
        hipGetSymbolAddress(&sp, HIP_SYMBOL(g_static_pool));
        if (sp == nullptr) {
            zero_out_kernel<<<(out_size + 255) / 256, 256, 0, stream>>>((float*)d_out, out_size);
            return;
        }
        base = (char*)sp;
    }
    size_t off = 0;
    auto nxt = [&](size_t bytes) { char* p = base + off; off += bytes; return p; };
    int*      deg      = (int*)nxt(SZ_DEG);
    int*      row_ptr  = (int*)nxt(SZ_RP);
    int*      cursor   = (int*)nxt(SZ_CUR);
    int*      col      = (int*)nxt(SZ_COL);
    float*    xT       = (float*)nxt(SZ_XT);
    float*    xagg     = (float*)nxt(SZ_XT);
    ushort_t* emb      = (ushort_t*)nxt(SZ_EMB);
    ushort_t* xin2     = (ushort_t*)nxt(SZ_NHB);
    ushort_t* h1       = (ushort_t*)nxt(SZ_NHB);
    ushort_t* h2       = (ushort_t*)nxt(SZ_NHB);
    ushort_t* wb_c1w2  = (ushort_t*)nxt(SZ_W128);
    ushort_t* wb_c2w1  = (ushort_t*)nxt(SZ_W128);
    ushort_t* wb_c2w2  = (ushort_t*)nxt(SZ_W128);
    ushort_t* wb_wih   = (ushort_t*)nxt(SZ_WGRU);
    ushort_t* wb_whh   = (ushort_t*)nxt(SZ_WGRU);

    const int NW = 3 * HID * HID + 2 * G3 * HID;
    cvt5_kernel<<<(NW + 255) / 256, 256, 0, stream>>>(c1_w2, wb_c1w2, HID * HID,
                                                      c2_w1, wb_c2w1, HID * HID,
                                                      c2_w2, wb_c2w2, HID * HID,
                                                      g_wih, wb_wih, G3 * HID,
                                                      g_whh, wb_whh, G3 * HID);

    init_kernel<<<(NN * HID + 255) / 256, 256, 0, stream>>>(deg, h1, h2);

    hist_kernel<<<(E + 255) / 256, 256, 0, stream>>>(e_dst, deg, E);
    scan_kernel<<<1, 1024, 0, stream>>>(deg, row_ptr, cursor, NN);
    scatter_kernel<<<(E + 255) / 256, 256, 0, stream>>>(e_src, e_dst, cursor, col, E);

    // conv1 for all timesteps: transpose -> single-pass all-plane gather -> compute
    transpose_x_kernel<<<(NN * TF12 + 255) / 256, 256, 0, stream>>>(x_seq, xT);
    agg12t_kernel<<<(NN + 7) / 8, 512, 0, stream>>>(xT, row_ptr, col, xagg, E);
    conv1c_all_kernel<<<dim3(NBLK, T_STEPS), 512, 0, stream>>>(xagg, emb,
                                                               c1_w1, c1_b1, c1_g, c1_be, c1_rm, c1_rv,
                                                               wb_c1w2, c1_b2);

    // t = 0 prologue
    gru_step_kernel<<<NBLK, 512, 0, stream>>>(emb, h1, wb_wih, wb_whh, g_bih, g_bhh);
    agg128b_kernel<<<(NN * 64 + 255) / 256, 256, 0, stream>>>(h1, row_ptr, col, xin2, E);
    // fused steady state: mega2(t) || gru_step(t+1), then agg(t+1)
    for (int t = 0; t < T_STEPS - 1; ++t) {
        fused_mg_kernel<<<2 * NBLK, 512, 0, stream>>>(xin2, h2,
                                                      wb_c2w1, c2_b1, c2_g, c2_be, c2_rm, c2_rv,
                                                      wb_c2w2, c2_b2,
                                                      wb_wih, wb_whh, g_bih, g_bhh,
                                                      emb + (size_t)(t + 1) * NN * HID, h1);
        agg128b_kernel<<<(NN * 64 + 255) / 256, 256, 0, stream>>>(h1, row_ptr, col, xin2, E);
    }
    // t = T-1 epilogue
    mega2_kernel<<<NBLK, 512, 0, stream>>>(xin2, h2,
                                           wb_c2w1, c2_b1, c2_g, c2_be, c2_rm, c2_rv,
                                           wb_c2w2, c2_b2,
                                           wb_wih, wb_whh, g_bih, g_bhh);

    head_kernel<<<BB, 64, 0, stream>>>(h2, t_idx, apart, f1_w, f1_b, f2_w, f2_b, f3_w, f3_b, (float*)d_out);
}